// Round 11
// baseline (3335.558 us; speedup 1.0000x reference)
//
#include <hip/hip_runtime.h>
#include <hip/hip_bf16.h>

// ============================================================================
// ROUND 11 = ABLATION PROBES. gemm's invariant ~31us (6 structures!) is
// split into A-supply (probe_a: stage-only, 64 reps) vs compute phase
// (probe_c: stage-once, compute 128 reps). Real r10 pipeline runs LAST,
// unchanged, so validation + absmax are identical. dur_us is sacrificial.
// ============================================================================

#define BATCH   8192
#define NGRP    8
#define MAXGS   64
#define DMODEL  2048
#define TM      16
#define TILES   (BATCH / TM)      // 512

typedef __attribute__((ext_vector_type(8))) short  short8;
typedef __attribute__((ext_vector_type(4))) float  f32x4;
typedef __attribute__((ext_vector_type(4))) short  short4v;

#define LISTS_OFF 1024
#define W_OFF (LISTS_OFF + NGRP * BATCH * 4)
#define CNT_STRIDE 16

static __device__ __forceinline__ short bf(float f) {
    __hip_bfloat16 h = __float2bfloat16(f);
    return (short)__bfloat16_as_ushort(h);
}

// Phase 0: zero padded counters + convert W (f32 -> bf16) into ws.
__global__ __launch_bounds__(256) void init_kernel(const float* __restrict__ W,
                                                   unsigned short* __restrict__ Wb,
                                                   int* __restrict__ cnt) {
    int idx = blockIdx.x * 256 + threadIdx.x;
    if (idx < NGRP * CNT_STRIDE) cnt[idx] = 0;
    int e = idx * 4;
    float4 w = *reinterpret_cast<const float4*>(W + e);
    ushort4 o;
    o.x = (unsigned short)bf(w.x); o.y = (unsigned short)bf(w.y);
    o.z = (unsigned short)bf(w.z); o.w = (unsigned short)bf(w.w);
    *reinterpret_cast<ushort4*>(Wb + e) = o;
}

// Phase 1: bucket samples by group (LDS-aggregated atomics).
__global__ __launch_bounds__(256) void bucket_kernel(const int* __restrict__ chosen,
                                                     int* __restrict__ cnt,
                                                     int* __restrict__ lists) {
    __shared__ int lcnt[NGRP];
    __shared__ int lbase[NGRP];
    int tid = threadIdx.x;
    int b = blockIdx.x * 256 + tid;
    int g = chosen[b];
    int lane = tid & 63;
    if (tid < NGRP) lcnt[tid] = 0;
    __syncthreads();

    int wbase = 0;
    unsigned long long mymask = 0;
    #pragma unroll
    for (int gg = 0; gg < NGRP; ++gg) {
        unsigned long long m = __ballot(g == gg);
        if (g == gg) {
            int leader = __ffsll(m) - 1;
            int wb_ = 0;
            if (lane == leader) wb_ = atomicAdd(&lcnt[gg], __popcll(m));
            wb_ = __shfl(wb_, leader);
            wbase = wb_;
            mymask = m;
        }
    }
    __syncthreads();
    if (tid < NGRP) lbase[tid] = atomicAdd(&cnt[tid * CNT_STRIDE], lcnt[tid]);
    __syncthreads();

    int pos = lbase[g] + wbase + __popcll(mymask & ((1ull << lane) - 1ull));
    lists[g * BATCH + pos] = b;
}

// ---------------- PROBE A: staging phase only, REPS reps ----------------
__global__ __launch_bounds__(256, 2) void probe_a(
    const float* __restrict__ hidden,
    const int* __restrict__ cnt,
    const int* __restrict__ lists)
{
    const int REPS = 64;
    int bid = blockIdx.x;
    int g = bid & (NGRP - 1);
    int t = bid >> 3;
    int c = cnt[g * CNT_STRIDE];
    int m0 = t * TM;
    if (m0 >= c) return;

    __shared__ unsigned short A[TM][DMODEL];
    int tid  = threadIdx.x;
    int w    = tid >> 6;
    int lane = tid & 63;

    const float* src[4];
    #pragma unroll
    for (int i = 0; i < 4; ++i) {
        int m  = m0 + 4 * w + i;
        int ms = m < c ? m : c - 1;
        src[i] = hidden + ((size_t)lists[g * BATCH + ms] * NGRP + g) * DMODEL
               + lane * 4;
    }

    int dep = 0;          // opaque 0: defeats cross-rep load CSE / dead stores
    int s = 0;
    for (int rep = 0; rep < REPS; ++rep) {
        asm volatile("" : "+v"(dep));
        f32x4 ra[8], rb[8];
        #pragma unroll
        for (int h = 0; h < 8; ++h)
            ra[h] = *reinterpret_cast<const f32x4*>(src[0] + dep + h * 256);
        #pragma unroll
        for (int h = 0; h < 8; ++h)
            rb[h] = *reinterpret_cast<const f32x4*>(src[1] + dep + h * 256);

        #pragma unroll
        for (int i = 0; i < 4; ++i) {
            int r = 4 * w + i;
            int swz = ((r & 7) << 4) | ((r & 1) << 6);
            char* abase = (char*)&A[r][0];
            #pragma unroll
            for (int h = 0; h < 8; ++h) {
                f32x4 v = ra[h];
                short4v o;
                o[0] = bf(v[0]); o[1] = bf(v[1]); o[2] = bf(v[2]); o[3] = bf(v[3]);
                int byte = (h * 512 + lane * 8) ^ swz;
                *reinterpret_cast<short4v*>(abase + byte) = o;
            }
            if (i < 3) {
                #pragma unroll
                for (int h = 0; h < 8; ++h) ra[h] = rb[h];
                if (i < 2) {
                    #pragma unroll
                    for (int h = 0; h < 8; ++h)
                        rb[h] = *reinterpret_cast<const f32x4*>(src[i + 2] + dep + h * 256);
                }
            }
        }
        __syncthreads();
        s += A[tid & 15][(tid * 131 + rep) & 2047];   // keep-alive read
        __syncthreads();
    }
    asm volatile("" :: "v"(s));
}

// ---------------- PROBE C: stage once, compute phase x REPS ----------------
__global__ __launch_bounds__(256, 2) void probe_c(
    const float* __restrict__ hidden,
    const float* __restrict__ bias,
    const int* __restrict__ gsizes,
    const int* __restrict__ cnt,
    const int* __restrict__ lists,
    const unsigned short* __restrict__ Wb,
    float* __restrict__ out)
{
    const int REPS = 128;
    int bid = blockIdx.x;
    int g = bid & (NGRP - 1);
    int t = bid >> 3;
    int c = cnt[g * CNT_STRIDE];
    int m0 = t * TM;
    if (m0 >= c) return;

    __shared__ unsigned short A[TM][DMODEL];
    int tid  = threadIdx.x;
    int w    = tid >> 6;
    int lane = tid & 63;
    int lrow = lane & 15;
    int kg   = lane >> 4;

    {   // stage once (r10 code)
        const float* src[4];
        #pragma unroll
        for (int i = 0; i < 4; ++i) {
            int m  = m0 + 4 * w + i;
            int ms = m < c ? m : c - 1;
            src[i] = hidden + ((size_t)lists[g * BATCH + ms] * NGRP + g) * DMODEL
                   + lane * 4;
        }
        f32x4 ra[8], rb[8];
        #pragma unroll
        for (int h = 0; h < 8; ++h)
            ra[h] = *reinterpret_cast<const f32x4*>(src[0] + h * 256);
        #pragma unroll
        for (int h = 0; h < 8; ++h)
            rb[h] = *reinterpret_cast<const f32x4*>(src[1] + h * 256);
        #pragma unroll
        for (int i = 0; i < 4; ++i) {
            int r = 4 * w + i;
            int swz = ((r & 7) << 4) | ((r & 1) << 6);
            char* abase = (char*)&A[r][0];
            #pragma unroll
            for (int h = 0; h < 8; ++h) {
                f32x4 v = ra[h];
                short4v o;
                o[0] = bf(v[0]); o[1] = bf(v[1]); o[2] = bf(v[2]); o[3] = bf(v[3]);
                int byte = (h * 512 + lane * 8) ^ swz;
                *reinterpret_cast<short4v*>(abase + byte) = o;
            }
            if (i < 3) {
                #pragma unroll
                for (int h = 0; h < 8; ++h) ra[h] = rb[h];
                if (i < 2) {
                    #pragma unroll
                    for (int h = 0; h < 8; ++h)
                        rb[h] = *reinterpret_cast<const f32x4*>(src[i + 2] + h * 256);
                }
            }
        }
    }
    __syncthreads();

    int swzr = ((lrow & 7) << 4) | ((lrow & 1) << 6);
    const char* arow = (const char*)&A[lrow][0];
    const unsigned short* bp =
        Wb + ((size_t)g * MAXGS + w * 16 + lrow) * DMODEL + kg * 8;
    int gsz = gsizes[g];
    int n = w * 16 + lrow;
    float bv = bias[g * MAXGS + n];

    int dep = 0;
    for (int rep = 0; rep < REPS; ++rep) {
        asm volatile("" : "+v"(dep));    // per-rep opaque: no hoist/fold
        f32x4 acc = f32x4{0, 0, 0, 0};
        #pragma unroll 8
        for (int kk = 0; kk < DMODEL / 32; ++kk) {
            int byte = (kk * 64 + kg * 16) ^ swzr;
            short8 af = *reinterpret_cast<const short8*>(arow + byte);
            short8 bfr = *reinterpret_cast<const short8*>(bp + dep + kk * 32);
            acc = __builtin_amdgcn_mfma_f32_16x16x32_bf16(af, bfr, acc, 0, 0, 0);
        }
        #pragma unroll
        for (int r = 0; r < 4; ++r) {
            int m = m0 + kg * 4 + r;
            if (m < c) {
                int s = lists[g * BATCH + m];
                out[(size_t)s * MAXGS + n] = acc[r] + bv;
                out[(size_t)(BATCH + s) * MAXGS + n] = (n < gsz) ? 1.0f : 0.0f;
            }
        }
    }
}

// ---------------- REAL gemm (r10, unchanged) ----------------
__global__ __launch_bounds__(256, 2) void gemm_kernel(
    const float* __restrict__ hidden,
    const float* __restrict__ bias,
    const int* __restrict__ gsizes,
    const int* __restrict__ cnt,
    const int* __restrict__ lists,
    const unsigned short* __restrict__ Wb,
    float* __restrict__ out)
{
    int bid = blockIdx.x;
    int g = bid & (NGRP - 1);
    int t = bid >> 3;
    int c = cnt[g * CNT_STRIDE];
    int m0 = t * TM;
    if (m0 >= c) return;

    __shared__ unsigned short A[TM][DMODEL];
    int tid  = threadIdx.x;
    int w    = tid >> 6;
    int lane = tid & 63;
    int lrow = lane & 15;
    int kg   = lane >> 4;

    {
        const float* src[4];
        #pragma unroll
        for (int i = 0; i < 4; ++i) {
            int m  = m0 + 4 * w + i;
            int ms = m < c ? m : c - 1;
            src[i] = hidden + ((size_t)lists[g * BATCH + ms] * NGRP + g) * DMODEL
                   + lane * 4;
        }
        f32x4 ra[8], rb[8];
        #pragma unroll
        for (int h = 0; h < 8; ++h)
            ra[h] = *reinterpret_cast<const f32x4*>(src[0] + h * 256);
        #pragma unroll
        for (int h = 0; h < 8; ++h)
            rb[h] = *reinterpret_cast<const f32x4*>(src[1] + h * 256);
        #pragma unroll
        for (int i = 0; i < 4; ++i) {
            int r = 4 * w + i;
            int swz = ((r & 7) << 4) | ((r & 1) << 6);
            char* abase = (char*)&A[r][0];
            #pragma unroll
            for (int h = 0; h < 8; ++h) {
                f32x4 v = ra[h];
                short4v o;
                o[0] = bf(v[0]); o[1] = bf(v[1]); o[2] = bf(v[2]); o[3] = bf(v[3]);
                int byte = (h * 512 + lane * 8) ^ swz;
                *reinterpret_cast<short4v*>(abase + byte) = o;
            }
            if (i < 3) {
                #pragma unroll
                for (int h = 0; h < 8; ++h) ra[h] = rb[h];
                if (i < 2) {
                    #pragma unroll
                    for (int h = 0; h < 8; ++h)
                        rb[h] = *reinterpret_cast<const f32x4*>(src[i + 2] + h * 256);
                }
            }
        }
    }
    __syncthreads();

    {
        int swzr = ((lrow & 7) << 4) | ((lrow & 1) << 6);
        const char* arow = (const char*)&A[lrow][0];
        const unsigned short* bp =
            Wb + ((size_t)g * MAXGS + w * 16 + lrow) * DMODEL + kg * 8;

        f32x4 acc = f32x4{0, 0, 0, 0};
        #pragma unroll 8
        for (int kk = 0; kk < DMODEL / 32; ++kk) {
            int byte = (kk * 64 + kg * 16) ^ swzr;
            short8 af = *reinterpret_cast<const short8*>(arow + byte);
            short8 bfr = *reinterpret_cast<const short8*>(bp + kk * 32);
            acc = __builtin_amdgcn_mfma_f32_16x16x32_bf16(af, bfr, acc, 0, 0, 0);
        }

        int gsz = gsizes[g];
        int n = w * 16 + lrow;
        float bv = bias[g * MAXGS + n];
        #pragma unroll
        for (int r = 0; r < 4; ++r) {
            int m = m0 + kg * 4 + r;
            if (m < c) {
                int s = lists[g * BATCH + m];
                out[(size_t)s * MAXGS + n] = acc[r] + bv;
                out[(size_t)(BATCH + s) * MAXGS + n] = (n < gsz) ? 1.0f : 0.0f;
            }
        }
    }
}

extern "C" void kernel_launch(void* const* d_in, const int* in_sizes, int n_in,
                              void* d_out, int out_size, void* d_ws, size_t ws_size,
                              hipStream_t stream) {
    const float* hidden = (const float*)d_in[0];
    const int*   chosen = (const int*)d_in[1];
    const float* W      = (const float*)d_in[2];
    const float* bias   = (const float*)d_in[3];
    const int*   gs     = (const int*)d_in[4];
    float* out = (float*)d_out;

    char* ws = (char*)d_ws;
    int* cnt   = (int*)ws;
    int* lists = (int*)(ws + LISTS_OFF);
    unsigned short* Wb = (unsigned short*)(ws + W_OFF);

    init_kernel<<<dim3(1024), dim3(256), 0, stream>>>(W, Wb, cnt);
    bucket_kernel<<<dim3(32), dim3(256), 0, stream>>>(chosen, cnt, lists);
    // PROBES (idempotent; outputs of probe_c overwritten by real gemm below)
    probe_a<<<dim3(NGRP * TILES), dim3(256), 0, stream>>>(hidden, cnt, lists);
    probe_c<<<dim3(NGRP * TILES), dim3(256), 0, stream>>>(
        hidden, bias, gs, cnt, lists, Wb, out);
    // REAL pipeline output (unchanged r10)
    gemm_kernel<<<dim3(NGRP * TILES), dim3(256), 0, stream>>>(
        hidden, bias, gs, cnt, lists, Wb, out);
}

// Round 12
// 49.869 us; speedup vs baseline: 66.8862x; 66.8862x over previous
//
#include <hip/hip_runtime.h>
#include <hip/hip_bf16.h>

// Problem constants
#define BATCH   8192
#define NGRP    8
#define MAXGS   64
#define DMODEL  2048
#define TM      16
#define TILES   (BATCH / TM)      // 512

typedef __attribute__((ext_vector_type(8))) short  short8;
typedef __attribute__((ext_vector_type(4))) float  f32x4;

#define LISTS_OFF 1024
#define W_OFF (LISTS_OFF + NGRP * BATCH * 4)
#define CNT_STRIDE 16   // ints; 64B line per counter

static __device__ __forceinline__ short bf(float f) {
    __hip_bfloat16 h = __float2bfloat16(f);
    return (short)__bfloat16_as_ushort(h);
}

// Phase 0: zero padded counters + convert W (f32 -> bf16) into ws.
__global__ __launch_bounds__(256) void init_kernel(const float* __restrict__ W,
                                                   unsigned short* __restrict__ Wb,
                                                   int* __restrict__ cnt) {
    int idx = blockIdx.x * 256 + threadIdx.x;
    if (idx < NGRP * CNT_STRIDE) cnt[idx] = 0;
    int e = idx * 4;
    float4 w = *reinterpret_cast<const float4*>(W + e);
    ushort4 o;
    o.x = (unsigned short)bf(w.x); o.y = (unsigned short)bf(w.y);
    o.z = (unsigned short)bf(w.z); o.w = (unsigned short)bf(w.w);
    *reinterpret_cast<ushort4*>(Wb + e) = o;
}

// Phase 1: bucket samples by group (LDS-aggregated atomics; order
// nondeterministic, per-sample output values order-independent).
__global__ __launch_bounds__(256) void bucket_kernel(const int* __restrict__ chosen,
                                                     int* __restrict__ cnt,
                                                     int* __restrict__ lists) {
    __shared__ int lcnt[NGRP];
    __shared__ int lbase[NGRP];
    int tid = threadIdx.x;
    int b = blockIdx.x * 256 + tid;
    int g = chosen[b];
    int lane = tid & 63;
    if (tid < NGRP) lcnt[tid] = 0;
    __syncthreads();

    int wbase = 0;
    unsigned long long mymask = 0;
    #pragma unroll
    for (int gg = 0; gg < NGRP; ++gg) {
        unsigned long long m = __ballot(g == gg);
        if (g == gg) {
            int leader = __ffsll(m) - 1;
            int wb_ = 0;
            if (lane == leader) wb_ = atomicAdd(&lcnt[gg], __popcll(m));
            wb_ = __shfl(wb_, leader);
            wbase = wb_;
            mymask = m;
        }
    }
    __syncthreads();
    if (tid < NGRP) lbase[tid] = atomicAdd(&cnt[tid * CNT_STRIDE], lcnt[tid]);
    __syncthreads();

    int pos = lbase[g] + wbase + __popcll(mymask & ((1ull << lane) - 1ull));
    lists[g * BATCH + pos] = b;
}

// Phase 2: LDS-FREE per-wave GEMM.
// WHY (r11 probes): compute phase with LDS-A = 22us/rep (1.35e8 bank
// conflicts, 8-way residual on ds_read_b128); gather+stage = only 7us.
// So: one 64-thread wave owns a whole 16-sample x 64-col tile. A lives in
// REGISTERS, gathered straight from hidden (each element read ONCE chip-wide;
// no cross-wave sharing -> no LDS, no barriers, no conflicts). B streams from
// L2-resident Wb. vmcnt in-order hazard handled by ISSUE ORDER: A-chunks are
// prefetched 3 chunks (~1400cy) ahead; B-loads issue later, so any B-wait
// only retires A-loads that already arrived. ~512 live waves, 2/CU, each
// with ~24 gather loads in flight -> 12MB outstanding >> BDP -> HBM-rate A.
// MFMA C/D: col = lane&15 (within col-group), row = (lane>>4)*4 + reg.
__global__ __launch_bounds__(64, 2) void gemm_kernel(
    const float* __restrict__ hidden,
    const float* __restrict__ bias,
    const int* __restrict__ gsizes,
    const int* __restrict__ cnt,
    const int* __restrict__ lists,
    const unsigned short* __restrict__ Wb,
    float* __restrict__ out)
{
    int bid = blockIdx.x;
    int g = bid & (NGRP - 1);      // group <-> XCD alignment: Wb[g] L2-resident
    int t = bid >> 3;
    int c = cnt[g * CNT_STRIDE];
    int m0 = t * TM;
    if (m0 >= c) return;           // dead block: instant exit (live bids are
                                   // dense in 0..~511 -> ~2 live waves/CU)
    int lane = threadIdx.x;        // 0..63
    int lrow = lane & 15;
    int kg   = lane >> 4;          // 0..3

    int mrow  = m0 + lrow;
    int msafe = mrow < c ? mrow : c - 1;     // tail: dup last row (guarded)
    int smp   = lists[g * BATCH + msafe];

    const float* __restrict__ ap =
        hidden + ((size_t)smp * NGRP + g) * DMODEL + kg * 8;
    const unsigned short* __restrict__ bp =
        Wb + ((size_t)g * MAXGS + lrow) * DMODEL + kg * 8;

    // A register ring: 4 chunks x (4 kk-steps x 2 f32x4) = 128 VGPR.
    // All indices compile-time (full unroll) -> no scratch (rule #20).
    f32x4 ra[4][8];
    f32x4 acc[4] = {f32x4{0,0,0,0}, f32x4{0,0,0,0}, f32x4{0,0,0,0}, f32x4{0,0,0,0}};

    // prologue: prefetch chunks 0..2 (12 kk-steps, 384B/lane in flight)
    #pragma unroll
    for (int pc = 0; pc < 3; ++pc)
        #pragma unroll
        for (int j = 0; j < 4; ++j) {
            ra[pc][2*j]   = *reinterpret_cast<const f32x4*>(ap + (pc*4 + j)*32);
            ra[pc][2*j+1] = *reinterpret_cast<const f32x4*>(ap + (pc*4 + j)*32 + 4);
        }

    #pragma unroll
    for (int ch = 0; ch < 16; ++ch) {          // 16 chunks x 128k = 2048
        if (ch + 3 < 16) {                      // prefetch 3 ahead
            #pragma unroll
            for (int j = 0; j < 4; ++j) {
                ra[(ch+3) & 3][2*j]   =
                    *reinterpret_cast<const f32x4*>(ap + ((ch+3)*4 + j)*32);
                ra[(ch+3) & 3][2*j+1] =
                    *reinterpret_cast<const f32x4*>(ap + ((ch+3)*4 + j)*32 + 4);
            }
        }
        #pragma unroll
        for (int j = 0; j < 4; ++j) {          // kk = ch*4 + j (K=32 each)
            f32x4 alo = ra[ch & 3][2*j];
            f32x4 ahi = ra[ch & 3][2*j+1];
            short8 af;
            af[0] = bf(alo[0]); af[1] = bf(alo[1]); af[2] = bf(alo[2]); af[3] = bf(alo[3]);
            af[4] = bf(ahi[0]); af[5] = bf(ahi[1]); af[6] = bf(ahi[2]); af[7] = bf(ahi[3]);
            int kk = ch*4 + j;
            #pragma unroll
            for (int cg = 0; cg < 4; ++cg) {   // 4 col-groups of 16
                short8 bfr = *reinterpret_cast<const short8*>(
                    bp + cg * 16 * DMODEL + kk * 32);
                acc[cg] = __builtin_amdgcn_mfma_f32_16x16x32_bf16(af, bfr, acc[cg], 0, 0, 0);
            }
        }
    }

    // epilogue: row = kg*4 + r, col = cg*16 + lrow
    int gsz = gsizes[g];
    #pragma unroll
    for (int r = 0; r < 4; ++r) {
        int m = m0 + kg * 4 + r;
        if (m < c) {
            int s = lists[g * BATCH + m];
            float* prow = out + (size_t)s * MAXGS;
            float* vrow = out + (size_t)(BATCH + s) * MAXGS;
            #pragma unroll
            for (int cg = 0; cg < 4; ++cg) {
                int n = cg * 16 + lrow;
                prow[n] = acc[cg][r] + bias[g * MAXGS + n];  // padded n: 0+0 == 0
                vrow[n] = (n < gsz) ? 1.0f : 0.0f;
            }
        }
    }
}

extern "C" void kernel_launch(void* const* d_in, const int* in_sizes, int n_in,
                              void* d_out, int out_size, void* d_ws, size_t ws_size,
                              hipStream_t stream) {
    const float* hidden = (const float*)d_in[0];   // [8192, 8, 2048] f32
    const int*   chosen = (const int*)d_in[1];     // [8192] i32
    const float* W      = (const float*)d_in[2];   // [8, 64, 2048] f32 (zero-padded)
    const float* bias   = (const float*)d_in[3];   // [8, 64] f32 (zero-padded)
    const int*   gs     = (const int*)d_in[4];     // [8] i32
    float* out = (float*)d_out;                    // [8192*64 preds | 8192*64 valid]

    char* ws = (char*)d_ws;
    int* cnt   = (int*)ws;
    int* lists = (int*)(ws + LISTS_OFF);
    unsigned short* Wb = (unsigned short*)(ws + W_OFF);

    init_kernel<<<dim3(1024), dim3(256), 0, stream>>>(W, Wb, cnt);
    bucket_kernel<<<dim3(32), dim3(256), 0, stream>>>(chosen, cnt, lists);
    gemm_kernel<<<dim3(NGRP * TILES), dim3(64), 0, stream>>>(
        hidden, bias, gs, cnt, lists, Wb, out);
}

// Round 13
// 49.362 us; speedup vs baseline: 67.5735x; 1.0103x over previous
//
#include <hip/hip_runtime.h>
#include <hip/hip_bf16.h>

// Problem constants
#define BATCH   8192
#define NGRP    8
#define MAXGS   64
#define DMODEL  2048
#define TM      16
#define TILES   (BATCH / TM)      // 512

typedef __attribute__((ext_vector_type(8))) short  short8;
typedef __attribute__((ext_vector_type(4))) float  f32x4;

#define LISTS_OFF 1024
#define W_OFF (LISTS_OFF + NGRP * BATCH * 4)
#define CNT_STRIDE 16   // ints; 64B line per counter
#define NKK     (DMODEL / 32)     // 64 K-chunks

static __device__ __forceinline__ short bf(float f) {
    __hip_bfloat16 h = __float2bfloat16(f);
    return (short)__bfloat16_as_ushort(h);
}

// Phase 0: zero padded counters + repack W (f32, [g][c][k]) into Wb2
// (bf16, [g][kk][c][j]) where k = kk*32 + j. WHY: the old row-major Wb put
// a wave's 16 concurrent B-rows at 4KB stride = SAME 256B-interleaved L2
// channel -> B streamed at ~1/16 L2 rate; this was the invariant ~31us wall
// across ALL seven structures (r11 probe_c re-read: bank conflicts were only
// 2Kcy/53Kcy -- the 22us was the B path). New layout: per-MFMA B-load is
// 1KB FULLY CONTIGUOUS (16 cols x 64B), channels rotate with kk.
__global__ __launch_bounds__(256) void init_kernel(const float* __restrict__ W,
                                                   unsigned short* __restrict__ Wb2,
                                                   int* __restrict__ cnt) {
    int idx = blockIdx.x * 256 + threadIdx.x;
    if (idx < NGRP * CNT_STRIDE) cnt[idx] = 0;
    int e = idx * 4;                       // 4 consecutive k of one (g,c) row
    int g = e >> 17;                       // / (64*2048)
    int rem = e & ((MAXGS * DMODEL) - 1);
    int c = rem >> 11;                     // / 2048
    int k = rem & (DMODEL - 1);
    int kk = k >> 5, j = k & 31;           // j aligned to 4
    float4 w = *reinterpret_cast<const float4*>(W + e);
    ushort4 o;
    o.x = (unsigned short)bf(w.x); o.y = (unsigned short)bf(w.y);
    o.z = (unsigned short)bf(w.z); o.w = (unsigned short)bf(w.w);
    size_t dst = (((size_t)g * NKK + kk) * MAXGS + c) * 32 + j;
    *reinterpret_cast<ushort4*>(Wb2 + dst) = o;
}

// Phase 1: bucket samples by group (LDS-aggregated atomics; order
// nondeterministic, per-sample output values order-independent).
__global__ __launch_bounds__(256) void bucket_kernel(const int* __restrict__ chosen,
                                                     int* __restrict__ cnt,
                                                     int* __restrict__ lists) {
    __shared__ int lcnt[NGRP];
    __shared__ int lbase[NGRP];
    int tid = threadIdx.x;
    int b = blockIdx.x * 256 + tid;
    int g = chosen[b];
    int lane = tid & 63;
    if (tid < NGRP) lcnt[tid] = 0;
    __syncthreads();

    int wbase = 0;
    unsigned long long mymask = 0;
    #pragma unroll
    for (int gg = 0; gg < NGRP; ++gg) {
        unsigned long long m = __ballot(g == gg);
        if (g == gg) {
            int leader = __ffsll(m) - 1;
            int wb_ = 0;
            if (lane == leader) wb_ = atomicAdd(&lcnt[gg], __popcll(m));
            wb_ = __shfl(wb_, leader);
            wbase = wb_;
            mymask = m;
        }
    }
    __syncthreads();
    if (tid < NGRP) lbase[tid] = atomicAdd(&cnt[tid * CNT_STRIDE], lcnt[tid]);
    __syncthreads();

    int pos = lbase[g] + wbase + __popcll(mymask & ((1ull << lane) - 1ull));
    lists[g * BATCH + pos] = b;
}

// Phase 2: LDS-free per-wave GEMM (r12 structure, ONLY the B layout changed).
// One 64-thread wave owns a 16-sample x 64-col tile; A in registers,
// gathered once chip-wide; B from coalesced Wb2 (1KB contiguous per MFMA).
// A-chunks prefetched 3 ahead (~1400cy); B-loads issue later so B-waits only
// retire already-arrived A loads (in-order vmcnt works for us).
// MFMA C/D: col = lane&15 (within col-group), row = (lane>>4)*4 + reg.
__global__ __launch_bounds__(64, 2) void gemm_kernel(
    const float* __restrict__ hidden,
    const float* __restrict__ bias,
    const int* __restrict__ gsizes,
    const int* __restrict__ cnt,
    const int* __restrict__ lists,
    const unsigned short* __restrict__ Wb2,
    float* __restrict__ out)
{
    int bid = blockIdx.x;
    int g = bid & (NGRP - 1);      // group <-> XCD alignment: Wb2[g] L2-resident
    int t = bid >> 3;
    int c = cnt[g * CNT_STRIDE];
    int m0 = t * TM;
    if (m0 >= c) return;           // dead block: instant exit

    int lane = threadIdx.x;        // 0..63
    int lrow = lane & 15;
    int kg   = lane >> 4;          // 0..3

    int mrow  = m0 + lrow;
    int msafe = mrow < c ? mrow : c - 1;     // tail: dup last row (guarded)
    int smp   = lists[g * BATCH + msafe];

    const float* __restrict__ ap =
        hidden + ((size_t)smp * NGRP + g) * DMODEL + kg * 8;
    // B: coalesced layout. Lane (lrow,kg), col-group cg, chunk kk loads
    // Wb2[g][kk][cg*16+lrow][kg*8 .. +8) -- wave covers 1KB contiguous.
    const unsigned short* __restrict__ bp =
        Wb2 + (size_t)g * NKK * MAXGS * 32 + lrow * 32 + kg * 8;

    f32x4 ra[4][8];
    f32x4 acc[4] = {f32x4{0,0,0,0}, f32x4{0,0,0,0}, f32x4{0,0,0,0}, f32x4{0,0,0,0}};

    // prologue: prefetch chunks 0..2 (96 f32/lane in flight)
    #pragma unroll
    for (int pc = 0; pc < 3; ++pc)
        #pragma unroll
        for (int j = 0; j < 4; ++j) {
            ra[pc][2*j]   = *reinterpret_cast<const f32x4*>(ap + (pc*4 + j)*32);
            ra[pc][2*j+1] = *reinterpret_cast<const f32x4*>(ap + (pc*4 + j)*32 + 4);
        }

    #pragma unroll
    for (int ch = 0; ch < 16; ++ch) {          // 16 chunks x K=128
        if (ch + 3 < 16) {                      // prefetch 3 ahead
            #pragma unroll
            for (int j = 0; j < 4; ++j) {
                ra[(ch+3) & 3][2*j]   =
                    *reinterpret_cast<const f32x4*>(ap + ((ch+3)*4 + j)*32);
                ra[(ch+3) & 3][2*j+1] =
                    *reinterpret_cast<const f32x4*>(ap + ((ch+3)*4 + j)*32 + 4);
            }
        }
        #pragma unroll
        for (int j = 0; j < 4; ++j) {          // kk = ch*4 + j
            f32x4 alo = ra[ch & 3][2*j];
            f32x4 ahi = ra[ch & 3][2*j+1];
            short8 af;
            af[0] = bf(alo[0]); af[1] = bf(alo[1]); af[2] = bf(alo[2]); af[3] = bf(alo[3]);
            af[4] = bf(ahi[0]); af[5] = bf(ahi[1]); af[6] = bf(ahi[2]); af[7] = bf(ahi[3]);
            int kk = ch*4 + j;
            #pragma unroll
            for (int cg = 0; cg < 4; ++cg) {   // 4 col-groups of 16
                short8 bfr = *reinterpret_cast<const short8*>(
                    bp + ((size_t)kk * MAXGS + cg * 16) * 32);
                acc[cg] = __builtin_amdgcn_mfma_f32_16x16x32_bf16(af, bfr, acc[cg], 0, 0, 0);
            }
        }
    }

    // epilogue: row = kg*4 + r, col = cg*16 + lrow
    int gsz = gsizes[g];
    #pragma unroll
    for (int r = 0; r < 4; ++r) {
        int m = m0 + kg * 4 + r;
        if (m < c) {
            int s = lists[g * BATCH + m];
            float* prow = out + (size_t)s * MAXGS;
            float* vrow = out + (size_t)(BATCH + s) * MAXGS;
            #pragma unroll
            for (int cg = 0; cg < 4; ++cg) {
                int n = cg * 16 + lrow;
                prow[n] = acc[cg][r] + bias[g * MAXGS + n];  // padded n: 0+0 == 0
                vrow[n] = (n < gsz) ? 1.0f : 0.0f;
            }
        }
    }
}

extern "C" void kernel_launch(void* const* d_in, const int* in_sizes, int n_in,
                              void* d_out, int out_size, void* d_ws, size_t ws_size,
                              hipStream_t stream) {
    const float* hidden = (const float*)d_in[0];   // [8192, 8, 2048] f32
    const int*   chosen = (const int*)d_in[1];     // [8192] i32
    const float* W      = (const float*)d_in[2];   // [8, 64, 2048] f32 (zero-padded)
    const float* bias   = (const float*)d_in[3];   // [8, 64] f32 (zero-padded)
    const int*   gs     = (const int*)d_in[4];     // [8] i32
    float* out = (float*)d_out;                    // [8192*64 preds | 8192*64 valid]

    char* ws = (char*)d_ws;
    int* cnt   = (int*)ws;
    int* lists = (int*)(ws + LISTS_OFF);
    unsigned short* Wb2 = (unsigned short*)(ws + W_OFF);

    init_kernel<<<dim3(1024), dim3(256), 0, stream>>>(W, Wb2, cnt);
    bucket_kernel<<<dim3(32), dim3(256), 0, stream>>>(chosen, cnt, lists);
    gemm_kernel<<<dim3(NGRP * TILES), dim3(64), 0, stream>>>(
        hidden, bias, gs, cnt, lists, Wb2, out);
}